// Round 10
// baseline (256.231 us; speedup 1.0000x reference)
//
#include <hip/hip_runtime.h>
#include <hip/hip_bf16.h>
#include <math.h>

#define BS   16
#define NQ   900
#define NCLS 1000
#define NT   100          // targets per batch (rows for LSA)
#define MQ   900          // queries (cols for LSA)
#define NCOL (BS * NT)    // 1600 total target columns
#define NSLOT 15          // ceil(MQ / 64)

// ---------------------------------------------------------------------------
// Kernel A: softmax stats + the transposed diagonal cost block (costT) only.
// Small (~20us) so the LSA can start ASAP; the big C write overlaps LSA.
// ---------------------------------------------------------------------------
__global__ __launch_bounds__(256) void statcost_kernel(
    const float* __restrict__ logits, const float* __restrict__ boxes,
    const int* __restrict__ ids, const float* __restrict__ tbox,
    float* __restrict__ stats, float* __restrict__ costT, int id_stride) {
  const int row = blockIdx.x;              // 0..14399
  const int b = row / NQ;
  const int q = row - b * NQ;
  const int tid = threadIdx.x, wave = tid >> 6, lane = tid & 63;

  __shared__ float lrow_s[NCLS];
  __shared__ float red[8];

  const float4* l4 = (const float4*)(logits + (size_t)row * NCLS);
  if (tid < NCLS / 4) ((float4*)lrow_s)[tid] = l4[tid];
  __syncthreads();

  float lmax = -INFINITY;
  for (int j = tid; j < NCLS; j += 256) lmax = fmaxf(lmax, lrow_s[j]);
  for (int o = 32; o > 0; o >>= 1) lmax = fmaxf(lmax, __shfl_xor(lmax, o, 64));
  if (lane == 0) red[wave] = lmax;
  __syncthreads();
  const float rmax = fmaxf(fmaxf(red[0], red[1]), fmaxf(red[2], red[3]));

  float psum = 0.f;
  for (int j = tid; j < NCLS; j += 256) psum += expf(lrow_s[j] - rmax);
  for (int o = 32; o > 0; o >>= 1) psum += __shfl_xor(psum, o, 64);
  if (lane == 0) red[4 + wave] = psum;
  __syncthreads();
  const float rsum = red[4] + red[5] + red[6] + red[7];
  if (tid == 0) { stats[2 * row] = rmax; stats[2 * row + 1] = rsum; }

  const float4 bb = *reinterpret_cast<const float4*>(boxes + (size_t)row * 4);
  for (int r = tid; r < NT; r += 256) {
    const int j = b * NT + r;
    const int id = ids[(size_t)j * id_stride];
    const float4 tb = *reinterpret_cast<const float4*>(tbox + (size_t)j * 4);
    float d = fabsf(bb.x - tb.x);
    d += fabsf(bb.y - tb.y);
    d += fabsf(bb.z - tb.z);
    d += fabsf(bb.w - tb.w);
    const float pr = expf(lrow_s[id] - rmax) / rsum;
    costT[((size_t)b * NT + r) * MQ + q] = d - pr;
  }
}

// ---------------------------------------------------------------------------
// Main kernel: blocks 0..15 run JV LSA with greedy DUAL initialization only
// (u[i] = row min, v = 0; every row still goes through the proven Dijkstra/
// augment machinery — rows whose argmin column is free finish in ONE
// iterate). Blocks 16.. write the full C matrix — overlaps the LSA.
// ---------------------------------------------------------------------------
__device__ __forceinline__ unsigned umin32(unsigned a, unsigned b) {
  return a < b ? a : b;
}

template <int CTRL>
__device__ __forceinline__ unsigned dpp_min_u32(unsigned x) {
  const unsigned o = (unsigned)__builtin_amdgcn_update_dpp(
      (int)x, (int)x, CTRL, 0xF, 0xF, false);
  return o < x ? o : x;
}

// full-wave u32 min -> uniform value (chain ends in lane 63)
__device__ __forceinline__ unsigned wave_min_u32(unsigned x) {
  x = dpp_min_u32<0xB1>(x);    // quad_perm xor1
  x = dpp_min_u32<0x4E>(x);    // quad_perm xor2
  x = dpp_min_u32<0x114>(x);   // row_shr:4
  x = dpp_min_u32<0x118>(x);   // row_shr:8
  x = dpp_min_u32<0x142>(x);   // row_bcast15
  x = dpp_min_u32<0x143>(x);   // row_bcast31
  return (unsigned)__builtin_amdgcn_readlane((int)x, 63);
}

__global__ __launch_bounds__(256) void main_kernel(
    const float* __restrict__ logits, const float* __restrict__ boxes,
    const int* __restrict__ ids, const float* __restrict__ tbox,
    const float* __restrict__ stats, const float* __restrict__ costT,
    float* __restrict__ C, float* __restrict__ out_i,
    float* __restrict__ out_j, int id_stride) {
  __shared__ float lrow_s[NCLS];
  __shared__ int p[MQ + 1];
  __shared__ int way[MQ + 65];   // [901..964] absorb pad writes; [0] dummy
  __shared__ int cols[NT];
  __shared__ float u_s[NT];

  if (blockIdx.x >= BS) {
    // ---------------- C-matrix path (overlaps LSA) ----------------
    const int row = blockIdx.x - BS;
    const int tid = threadIdx.x;
    const float4* l4 = (const float4*)(logits + (size_t)row * NCLS);
    if (tid < NCLS / 4) ((float4*)lrow_s)[tid] = l4[tid];
    __syncthreads();
    const float rmax = stats[2 * row];
    const float rsum = stats[2 * row + 1];
    const float4 bb = *reinterpret_cast<const float4*>(boxes + (size_t)row * 4);
    float* crow = C + (size_t)row * NCOL;
    for (int j = tid; j < NCOL; j += 256) {
      const int id = ids[(size_t)j * id_stride];
      const float4 tb = *reinterpret_cast<const float4*>(tbox + (size_t)j * 4);
      float d = fabsf(bb.x - tb.x);
      d += fabsf(bb.y - tb.y);
      d += fabsf(bb.z - tb.z);
      d += fabsf(bb.w - tb.w);
      crow[j] = d - expf(lrow_s[id] - rmax) / rsum;
    }
    return;
  }

  // ---------------- LSA path: one wave per batch ----------------
  if (threadIdx.x >= 64) return;
  const int b = blockIdx.x;
  const float* cost = costT + (size_t)b * NT * MQ;
  const int lane = threadIdx.x;
  const float FINF = __builtin_inff();
  const unsigned UMAX = 0xFFFFFFFFu;
  const unsigned UINFB = 0x7F800000u;    // +inf f32 bits

  float v[NSLOT];
  unsigned V32[NSLOT];           // stored (minv + D) as f32 bits; frozen on use
  float cfA[NSLOT], cfB[NSLOT], cfI[NSLOT];
  int jp[NSLOT];                 // (j << 7) | p[j] for this lane's columns
  float u0 = 0.f, u1 = 0.f;      // u[lane+1], u[lane+65]

#pragma unroll
  for (int s = 0; s < NSLOT; ++s) v[s] = 0.f;
  for (int j = lane; j <= MQ; j += 64) p[j] = 0;

  // ---- Phase 0: row minima -> u_s (pipelined; also warms L2) ----
  {
#pragma unroll
    for (int s = 0; s < NSLOT; ++s) {
      const int c = s * 64 + lane;
      cfA[s] = (c < MQ) ? cost[c] : FINF;
    }
    int rr = 0;
    auto rowmin_step = [&](float (&CUR)[NSLOT], float (&NXT)[NSLOT]) {
      const int rn = rr + 1;
      if (rn < NT) {
        const float* crow = cost + (size_t)rn * MQ;
#pragma unroll
        for (int s = 0; s < NSLOT; ++s) {
          const int c = s * 64 + lane;
          NXT[s] = (c < MQ) ? crow[c] : FINF;
        }
      }
      unsigned m[NSLOT];
#pragma unroll
      for (int s = 0; s < NSLOT; ++s) {
        const int c = s * 64 + lane;
        unsigned eb = __float_as_uint(CUR[s]);
        eb = (eb & 0x80000000u) ? ~eb : (eb | 0x80000000u);  // order-preserving
        m[s] = (c < MQ) ? eb : UMAX;
      }
#pragma unroll
      for (int st = 1; st < NSLOT; st <<= 1) {
#pragma unroll
        for (int s = 0; s + st < NSLOT; s += 2 * st)
          m[s] = umin32(m[s], m[s + st]);
      }
      const unsigned s_vb = wave_min_u32(m[0]);
      const unsigned ub = (s_vb & 0x80000000u) ? (s_vb ^ 0x80000000u) : ~s_vb;
      if (lane == 0) u_s[rr] = __uint_as_float(ub);
      ++rr;
    };
    while (rr < NT) {
      rowmin_step(cfA, cfB);
      if (rr >= NT) break;
      rowmin_step(cfB, cfA);
    }
    // distribute u to registers (row = lane, row = 64+lane)
    u0 = u_s[lane];
    u1 = (lane < NT - 64) ? u_s[64 + lane] : 0.f;
    // reload row 0 as the first pivot (L2-warm)
#pragma unroll
    for (int s = 0; s < NSLOT; ++s) {
      const int c = s * 64 + lane;
      cfA[s] = (c < MQ) ? cost[c] : FINF;
    }
  }

#pragma unroll
  for (int s = 0; s < NSLOT; ++s) {
    const int c = s * 64 + lane;
    if (c < MQ) jp[s] = (c + 1) << 7;          // p[c+1] = 0
  }

  for (int i = 1; i <= NT; ++i) {
    // pad columns (c >= MQ, slot 14 lanes >= 4) are permanently "used"
    unsigned usedm = (lane >= MQ - 14 * 64) ? (1u << 14) : 0u;
    int tm0 = 0, tm1 = 0;        // tree membership of owned rows
    float D = 0.f;               // accumulated delta offset
#pragma unroll
    for (int s = 0; s < NSLOT; ++s) V32[s] = UINFB;
    if (lane == 0) p[0] = i;

    // prefetch the NEXT Dijkstra's initial pivot row (0-based row i)
    if (i < NT) {
      const float* crow = cost + (size_t)i * MQ;
#pragma unroll
      for (int s = 0; s < NSLOT; ++s) {
        const int c = s * 64 + lane;
        cfI[s] = (c < MQ) ? crow[c] : FINF;
      }
    }

    // u[i] from distributed registers (greedy dual init: row minimum)
    float uir;
    {
      const int r = i - 1;
      const float uu = (r < 64) ? u0 : u1;
      uir = __uint_as_float(
          (unsigned)__builtin_amdgcn_readlane((int)__float_as_uint(uu),
                                              r & 63));
    }

    int j0 = 0;
    int i0 = i;
    float ui0 = uir;

    auto iterate = [&](float (&CUR)[NSLOT], float (&NXT)[NSLOT]) -> bool {
      // column j0 becomes used (j0 == 0 is the virtual column)
      if (j0 > 0) {
        const int cz = j0 - 1;
        const bool own = (lane == (cz & 63));
        usedm |= own ? (1u << (cz >> 6)) : 0u;
      }
      // row i0 joins the tree (receives +delta from this iteration on)
      {
        const int ri = i0 - 1;
        tm0 |= (lane == ri) ? 1 : 0;
        tm1 |= (lane == (ri - 64)) ? 1 : 0;
      }

      const float a = ui0 - D;   // scan in offset space: rel = cur + D
      unsigned tv[NSLOT];
#pragma unroll
      for (int s = 0; s < NSLOT; ++s) {
        const bool us = (usedm >> s) & 1u;
        const float rel = fmaxf(CUR[s] - a - v[s], 0.f);
        const unsigned rb = __float_as_uint(rel);
        const unsigned rbg = us ? UMAX : rb;   // used cols never relax
        const bool upd = rbg < V32[s];
        way[upd ? (s * 64 + lane + 1) : 0] = j0;
        V32[s] = upd ? rbg : V32[s];
        tv[s] = us ? UMAX : V32[s];            // tree never picks used cols
      }
      // phase 1: value-only u32 min
      unsigned m[NSLOT];
#pragma unroll
      for (int s = 0; s < NSLOT; ++s) m[s] = tv[s];
#pragma unroll
      for (int st = 1; st < NSLOT; st <<= 1) {
#pragma unroll
        for (int s = 0; s + st < NSLOT; s += 2 * st)
          m[s] = umin32(m[s], m[s + st]);
      }
      const unsigned s_best = wave_min_u32(m[0]);
      const float Dnew = __uint_as_float(s_best);

      // phase 2: first-index tie-break — min over (j<<7|p) of candidates
      unsigned cj[NSLOT];
#pragma unroll
      for (int s = 0; s < NSLOT; ++s)
        cj[s] = (tv[s] == s_best) ? (unsigned)jp[s] : UMAX;
#pragma unroll
      for (int st = 1; st < NSLOT; st <<= 1) {
#pragma unroll
        for (int s = 0; s + st < NSLOT; s += 2 * st)
          cj[s] = umin32(cj[s], cj[s + st]);
      }
      const unsigned jpw = wave_min_u32(cj[0]);
      const int j1 = (int)(jpw >> 7);
      const int pj1 = (int)(jpw & 127u);       // p[j1], carried in the key

      // prefetch next pivot row immediately
      if (pj1 != 0) {
        const float* crow = cost + (size_t)(pj1 - 1) * MQ;
#pragma unroll
        for (int s = 0; s < NSLOT; ++s) {
          const int c = s * 64 + lane;
          NXT[s] = (c < MQ) ? crow[c] : FINF;
        }
      }
      // u[pj1] from distributed registers (row not yet in tree -> exact)
      float unext = 0.f;
      if (pj1 != 0) {
        const int rr2 = pj1 - 1;
        const float uu = (rr2 < 64) ? u0 : u1;
        unext = __uint_as_float(
            (unsigned)__builtin_amdgcn_readlane((int)__float_as_uint(uu),
                                                rr2 & 63));
      }

      const float delta = Dnew - D;
      D = Dnew;                  // minv/v updates absorbed by the offset
      u0 += tm0 ? delta : 0.f;
      u1 += tm1 ? delta : 0.f;

      j0 = j1; i0 = pj1; ui0 = unext;
      return pj1 != 0;
    };

    while (true) {
      if (!iterate(cfA, cfB)) break;
      if (!iterate(cfB, cfA)) break;
    }

    // deferred v fixup: used column's use-time offset == frozen V32 value
    {
      const float Dend = D;
#pragma unroll
      for (int s = 0; s < NSLOT; ++s) {
        const int c = s * 64 + lane;
        const bool us = (usedm >> s) & 1u;
        const float dv = __uint_as_float(V32[s]) - Dend;
        v[s] += (us && c < MQ) ? dv : 0.f;
      }
    }

    // augment along the alternating path (serial, lane 0)
    if (lane == 0) {
      int ja = j0;
      while (ja != 0) { const int jb = way[ja]; p[ja] = p[jb]; ja = jb; }
    }
    // rebuild the packed jp registers from p (wave-synchronous LDS RAW)
#pragma unroll
    for (int s = 0; s < NSLOT; ++s) {
      const int c = s * 64 + lane;
      if (c < MQ) jp[s] = ((c + 1) << 7) | p[c + 1];
    }
    // rotate in the prefetched initial row for Dijkstra i+1
    if (i < NT) {
#pragma unroll
      for (int s = 0; s < NSLOT; ++s) cfA[s] = cfI[s];
    }
  }

  // extract assignment: cols[row] = column
  for (int j = lane + 1; j <= MQ; j += 64)
    if (p[j] > 0) cols[p[j] - 1] = j - 1;

  // order = argsort(cols); idx_i = cols[order], idx_j = order
  for (int r = lane; r < NT; r += 64) {
    const int c = cols[r];
    int rank = 0;
    for (int r2 = 0; r2 < NT; ++r2) rank += (cols[r2] < c);
    out_i[b * NT + rank] = (float)c;
    out_j[b * NT + rank] = (float)r;
  }
}

extern "C" void kernel_launch(void* const* d_in, const int* in_sizes, int n_in,
                              void* d_out, int out_size, void* d_ws,
                              size_t ws_size, hipStream_t stream) {
  const float* logits = (const float*)d_in[0];
  const float* boxes  = (const float*)d_in[1];
  const int*   ids    = (const int*)d_in[2];
  const float* tbox   = (const float*)d_in[3];

  float* C     = (float*)d_out;                      // 16*900*1600
  float* out_i = C + (size_t)BS * NQ * NCOL;         // 1600
  float* out_j = out_i + NCOL;                       // 1600

  float* costT = (float*)d_ws;                       // 16*100*900 floats
  float* stats = costT + (size_t)BS * NT * MQ;       // 2 * 14400 floats

  const int id_stride = (in_sizes[2] == 2 * NCOL) ? 2 : 1;

  statcost_kernel<<<BS * NQ, 256, 0, stream>>>(logits, boxes, ids, tbox,
                                               stats, costT, id_stride);
  main_kernel<<<BS * NQ + BS, 256, 0, stream>>>(logits, boxes, ids, tbox,
                                                stats, costT, C, out_i, out_j,
                                                id_stride);
}

// Round 12
// 144.977 us; speedup vs baseline: 1.7674x; 1.7674x over previous
//
#include <hip/hip_runtime.h>
#include <hip/hip_bf16.h>
#include <math.h>

#define BS   16
#define NQ   900
#define NCLS 1000
#define NT   100          // targets per batch (rows for LSA)
#define MQ   900          // queries (cols for LSA)
#define NCOL (BS * NT)    // 1600 total target columns
#define NSLOT 15          // ceil(MQ / 64)

// Compiler-only fence: pins program order of LDS ops around cross-lane
// handoffs (lane-0 ds_write -> all-lane ds_read). HW DS pipe is in-order
// per wave, so program order == visibility order within one wave.
#define WAVE_FENCE() asm volatile("" ::: "memory")

// ---------------------------------------------------------------------------
// Kernel A: softmax stats + the transposed diagonal cost block (costT) only.
// ---------------------------------------------------------------------------
__global__ __launch_bounds__(256) void statcost_kernel(
    const float* __restrict__ logits, const float* __restrict__ boxes,
    const int* __restrict__ ids, const float* __restrict__ tbox,
    float* __restrict__ stats, float* __restrict__ costT, int id_stride) {
  const int row = blockIdx.x;              // 0..14399
  const int b = row / NQ;
  const int q = row - b * NQ;
  const int tid = threadIdx.x, wave = tid >> 6, lane = tid & 63;

  __shared__ float lrow_s[NCLS];
  __shared__ float red[8];

  const float4* l4 = (const float4*)(logits + (size_t)row * NCLS);
  if (tid < NCLS / 4) ((float4*)lrow_s)[tid] = l4[tid];
  __syncthreads();

  float lmax = -INFINITY;
  for (int j = tid; j < NCLS; j += 256) lmax = fmaxf(lmax, lrow_s[j]);
  for (int o = 32; o > 0; o >>= 1) lmax = fmaxf(lmax, __shfl_xor(lmax, o, 64));
  if (lane == 0) red[wave] = lmax;
  __syncthreads();
  const float rmax = fmaxf(fmaxf(red[0], red[1]), fmaxf(red[2], red[3]));

  float psum = 0.f;
  for (int j = tid; j < NCLS; j += 256) psum += expf(lrow_s[j] - rmax);
  for (int o = 32; o > 0; o >>= 1) psum += __shfl_xor(psum, o, 64);
  if (lane == 0) red[4 + wave] = psum;
  __syncthreads();
  const float rsum = red[4] + red[5] + red[6] + red[7];
  if (tid == 0) { stats[2 * row] = rmax; stats[2 * row + 1] = rsum; }

  const float4 bb = *reinterpret_cast<const float4*>(boxes + (size_t)row * 4);
  for (int r = tid; r < NT; r += 256) {
    const int j = b * NT + r;
    const int id = ids[(size_t)j * id_stride];
    const float4 tb = *reinterpret_cast<const float4*>(tbox + (size_t)j * 4);
    float d = fabsf(bb.x - tb.x);
    d += fabsf(bb.y - tb.y);
    d += fabsf(bb.z - tb.z);
    d += fabsf(bb.w - tb.w);
    const float pr = expf(lrow_s[id] - rmax) / rsum;
    costT[((size_t)b * NT + r) * MQ + q] = d - pr;
  }
}

// ---------------------------------------------------------------------------
// Main kernel: blocks 0..15 run JV LSA with greedy duals AND serial (lane-0)
// greedy pre-assignment — claimed rows skip their Dijkstra entirely (~94 of
// 100). Blocks 16.. write the full C matrix — overlaps the LSA.
// ---------------------------------------------------------------------------
__device__ __forceinline__ unsigned umin32(unsigned a, unsigned b) {
  return a < b ? a : b;
}

template <int CTRL>
__device__ __forceinline__ unsigned dpp_min_u32(unsigned x) {
  const unsigned o = (unsigned)__builtin_amdgcn_update_dpp(
      (int)x, (int)x, CTRL, 0xF, 0xF, false);
  return o < x ? o : x;
}

// full-wave u32 min -> uniform value (chain ends in lane 63)
__device__ __forceinline__ unsigned wave_min_u32(unsigned x) {
  x = dpp_min_u32<0xB1>(x);    // quad_perm xor1
  x = dpp_min_u32<0x4E>(x);    // quad_perm xor2
  x = dpp_min_u32<0x114>(x);   // row_shr:4
  x = dpp_min_u32<0x118>(x);   // row_shr:8
  x = dpp_min_u32<0x142>(x);   // row_bcast15
  x = dpp_min_u32<0x143>(x);   // row_bcast31
  return (unsigned)__builtin_amdgcn_readlane((int)x, 63);
}

__global__ __launch_bounds__(256) void main_kernel(
    const float* __restrict__ logits, const float* __restrict__ boxes,
    const int* __restrict__ ids, const float* __restrict__ tbox,
    const float* __restrict__ stats, const float* __restrict__ costT,
    float* __restrict__ C, float* __restrict__ out_i,
    float* __restrict__ out_j, int id_stride) {
  __shared__ float lrow_s[NCLS];
  __shared__ int p[MQ + 1];
  __shared__ int way[MQ + 65];   // [901..964] absorb pad writes; [0] dummy
  __shared__ int cols[NT];
  __shared__ int amin_s[NT];
  __shared__ float u_s[NT];
  __shared__ unsigned long long claimed_s[2];

  if (blockIdx.x >= BS) {
    // ---------------- C-matrix path (overlaps LSA) ----------------
    const int row = blockIdx.x - BS;
    const int tid = threadIdx.x;
    const float4* l4 = (const float4*)(logits + (size_t)row * NCLS);
    if (tid < NCLS / 4) ((float4*)lrow_s)[tid] = l4[tid];
    __syncthreads();
    const float rmax = stats[2 * row];
    const float rsum = stats[2 * row + 1];
    const float4 bb = *reinterpret_cast<const float4*>(boxes + (size_t)row * 4);
    float* crow = C + (size_t)row * NCOL;
    for (int j = tid; j < NCOL; j += 256) {
      const int id = ids[(size_t)j * id_stride];
      const float4 tb = *reinterpret_cast<const float4*>(tbox + (size_t)j * 4);
      float d = fabsf(bb.x - tb.x);
      d += fabsf(bb.y - tb.y);
      d += fabsf(bb.z - tb.z);
      d += fabsf(bb.w - tb.w);
      crow[j] = d - expf(lrow_s[id] - rmax) / rsum;
    }
    return;
  }

  // ---------------- LSA path: one wave per batch ----------------
  if (threadIdx.x >= 64) return;
  const int b = blockIdx.x;
  const float* cost = costT + (size_t)b * NT * MQ;
  const int lane = threadIdx.x;
  const float FINF = __builtin_inff();
  const unsigned UMAX = 0xFFFFFFFFu;
  const unsigned UINFB = 0x7F800000u;    // +inf f32 bits

  float v[NSLOT];
  unsigned V32[NSLOT];           // stored (minv + D) as f32 bits; frozen on use
  float cfA[NSLOT], cfB[NSLOT];
  int jp[NSLOT];                 // (j << 7) | p[j] for this lane's columns
  float u0 = 0.f, u1 = 0.f;      // u[lane+1], u[lane+65]

#pragma unroll
  for (int s = 0; s < NSLOT; ++s) v[s] = 0.f;
  for (int j = lane; j <= MQ; j += 64) p[j] = 0;
  for (int r2 = lane; r2 < NT; r2 += 64) cols[r2] = -7777;  // diag sentinel
  WAVE_FENCE();   // p/cols zero-init visible before any cross-lane read

  // ---- Phase 0: row minima + argmin -> u_s / amin_s (pipelined) ----
  {
#pragma unroll
    for (int s = 0; s < NSLOT; ++s) {
      const int c = s * 64 + lane;
      cfA[s] = (c < MQ) ? cost[c] : FINF;
    }
    int rr = 0;
    auto rowmin_step = [&](float (&CUR)[NSLOT], float (&NXT)[NSLOT]) {
      const int rn = rr + 1;
      if (rn < NT) {
        const float* crow = cost + (size_t)rn * MQ;
#pragma unroll
        for (int s = 0; s < NSLOT; ++s) {
          const int c = s * 64 + lane;
          NXT[s] = (c < MQ) ? crow[c] : FINF;
        }
      }
      unsigned tv[NSLOT];
#pragma unroll
      for (int s = 0; s < NSLOT; ++s) {
        const int c = s * 64 + lane;
        unsigned eb = __float_as_uint(CUR[s]);
        eb = (eb & 0x80000000u) ? ~eb : (eb | 0x80000000u);  // order-preserving
        tv[s] = (c < MQ) ? eb : UMAX;
      }
      unsigned m[NSLOT];
#pragma unroll
      for (int s = 0; s < NSLOT; ++s) m[s] = tv[s];
#pragma unroll
      for (int st = 1; st < NSLOT; st <<= 1) {
#pragma unroll
        for (int s = 0; s + st < NSLOT; s += 2 * st)
          m[s] = umin32(m[s], m[s + st]);
      }
      const unsigned s_vb = wave_min_u32(m[0]);
      unsigned cj[NSLOT];
#pragma unroll
      for (int s = 0; s < NSLOT; ++s)
        cj[s] = (tv[s] == s_vb) ? (unsigned)(s * 64 + lane) : UMAX;
#pragma unroll
      for (int st = 1; st < NSLOT; st <<= 1) {
#pragma unroll
        for (int s = 0; s + st < NSLOT; s += 2 * st)
          cj[s] = umin32(cj[s], cj[s + st]);
      }
      const unsigned s_j = wave_min_u32(cj[0]);
      const unsigned ub = (s_vb & 0x80000000u) ? (s_vb ^ 0x80000000u) : ~s_vb;
      if (lane == 0) {
        amin_s[rr] = (int)s_j;
        u_s[rr] = __uint_as_float(ub);
      }
      ++rr;
    };
    while (rr < NT) {
      rowmin_step(cfA, cfB);
      if (rr >= NT) break;
      rowmin_step(cfB, cfA);
    }
    WAVE_FENCE();   // u_s/amin_s writes (lane 0) before all-lane reads
    // distribute u to registers (row = lane, row = 64+lane)
    u0 = u_s[lane];
    u1 = (lane < NT - 64) ? u_s[64 + lane] : 0.f;
  }

  // ---- Serial greedy pre-assignment (lane 0): first row wins its argmin.
  // Claimed edges are exactly tight (cost - rowmin - 0 == 0 in f32) ->
  // valid JV dual state. No parallel p[] writes, no lost rows.
  if (lane == 0) {
    unsigned long long c0 = 0, c1 = 0;
    for (int r2 = 0; r2 < NT; ++r2) {
      const int aj = amin_s[r2] + 1;       // 1-based column
      if (p[aj] == 0) {
        p[aj] = r2 + 1;
        if (r2 < 64) c0 |= 1ull << r2;
        else         c1 |= 1ull << (r2 - 64);
      }
    }
    claimed_s[0] = c0;
    claimed_s[1] = c1;
  }
  WAVE_FENCE();   // claim writes (lane 0) before all-lane mask/p reads
  const unsigned long long cl0 = claimed_s[0];
  const unsigned long long cl1 = claimed_s[1];

  // initial packed jp from the claimed p
#pragma unroll
  for (int s = 0; s < NSLOT; ++s) {
    const int c = s * 64 + lane;
    if (c < MQ) jp[s] = ((c + 1) << 7) | p[c + 1];
  }

  // ---- Dijkstra loop (proven R10 structure); claimed rows skip ----
  for (int i = 1; i <= NT; ++i) {
    const int r = i - 1;
    const bool skip = (r < 64) ? ((cl0 >> r) & 1ull) : ((cl1 >> (r - 64)) & 1ull);
    if (skip) continue;

    // load pivot row r (L2-warm from phase 0)
    {
      const float* crow = cost + (size_t)r * MQ;
#pragma unroll
      for (int s = 0; s < NSLOT; ++s) {
        const int c = s * 64 + lane;
        cfA[s] = (c < MQ) ? crow[c] : FINF;
      }
    }
    // u[i] from distributed registers (greedy dual: row minimum)
    float uir;
    {
      const float uu = (r < 64) ? u0 : u1;
      uir = __uint_as_float(
          (unsigned)__builtin_amdgcn_readlane((int)__float_as_uint(uu),
                                              r & 63));
    }

    // pad columns (c >= MQ, slot 14 lanes >= 4) are permanently "used"
    unsigned usedm = (lane >= MQ - 14 * 64) ? (1u << 14) : 0u;
    int tm0 = 0, tm1 = 0;        // tree membership of owned rows
    float D = 0.f;               // accumulated delta offset
#pragma unroll
    for (int s = 0; s < NSLOT; ++s) V32[s] = UINFB;
    if (lane == 0) p[0] = i;
    WAVE_FENCE();

    int j0 = 0;
    int i0 = i;
    float ui0 = uir;

    auto iterate = [&](float (&CUR)[NSLOT], float (&NXT)[NSLOT]) -> bool {
      // column j0 becomes used (j0 == 0 is the virtual column)
      if (j0 > 0) {
        const int cz = j0 - 1;
        const bool own = (lane == (cz & 63));
        usedm |= own ? (1u << (cz >> 6)) : 0u;
      }
      // row i0 joins the tree (receives +delta from this iteration on)
      {
        const int ri = i0 - 1;
        tm0 |= (lane == ri) ? 1 : 0;
        tm1 |= (lane == (ri - 64)) ? 1 : 0;
      }

      const float a = ui0 - D;   // scan in offset space: rel = cur + D
      unsigned tv[NSLOT];
#pragma unroll
      for (int s = 0; s < NSLOT; ++s) {
        const bool us = (usedm >> s) & 1u;
        const float rel = fmaxf(CUR[s] - a - v[s], 0.f);
        const unsigned rb = __float_as_uint(rel);
        const unsigned rbg = us ? UMAX : rb;   // used cols never relax
        const bool upd = rbg < V32[s];
        way[upd ? (s * 64 + lane + 1) : 0] = j0;
        V32[s] = upd ? rbg : V32[s];
        tv[s] = us ? UMAX : V32[s];            // tree never picks used cols
      }
      // phase 1: value-only u32 min
      unsigned m[NSLOT];
#pragma unroll
      for (int s = 0; s < NSLOT; ++s) m[s] = tv[s];
#pragma unroll
      for (int st = 1; st < NSLOT; st <<= 1) {
#pragma unroll
        for (int s = 0; s + st < NSLOT; s += 2 * st)
          m[s] = umin32(m[s], m[s + st]);
      }
      const unsigned s_best = wave_min_u32(m[0]);
      const float Dnew = __uint_as_float(s_best);

      // phase 2: first-index tie-break — min over (j<<7|p) of candidates
      unsigned cj[NSLOT];
#pragma unroll
      for (int s = 0; s < NSLOT; ++s)
        cj[s] = (tv[s] == s_best) ? (unsigned)jp[s] : UMAX;
#pragma unroll
      for (int st = 1; st < NSLOT; st <<= 1) {
#pragma unroll
        for (int s = 0; s + st < NSLOT; s += 2 * st)
          cj[s] = umin32(cj[s], cj[s + st]);
      }
      const unsigned jpw = wave_min_u32(cj[0]);
      const int j1 = (int)(jpw >> 7);
      const int pj1 = (int)(jpw & 127u);       // p[j1], carried in the key

      // prefetch next pivot row immediately
      if (pj1 != 0) {
        const float* crow = cost + (size_t)(pj1 - 1) * MQ;
#pragma unroll
        for (int s = 0; s < NSLOT; ++s) {
          const int c = s * 64 + lane;
          NXT[s] = (c < MQ) ? crow[c] : FINF;
        }
      }
      // u[pj1] from distributed registers (row not yet in tree -> exact)
      float unext = 0.f;
      if (pj1 != 0) {
        const int rr2 = pj1 - 1;
        const float uu = (rr2 < 64) ? u0 : u1;
        unext = __uint_as_float(
            (unsigned)__builtin_amdgcn_readlane((int)__float_as_uint(uu),
                                                rr2 & 63));
      }

      const float delta = Dnew - D;
      D = Dnew;                  // minv/v updates absorbed by the offset
      u0 += tm0 ? delta : 0.f;
      u1 += tm1 ? delta : 0.f;

      j0 = j1; i0 = pj1; ui0 = unext;
      return pj1 != 0;
    };

    while (true) {
      if (!iterate(cfA, cfB)) break;
      if (!iterate(cfB, cfA)) break;
    }

    // deferred v fixup: used column's use-time offset == frozen V32 value
    {
      const float Dend = D;
#pragma unroll
      for (int s = 0; s < NSLOT; ++s) {
        const int c = s * 64 + lane;
        const bool us = (usedm >> s) & 1u;
        const float dv = __uint_as_float(V32[s]) - Dend;
        v[s] += (us && c < MQ) ? dv : 0.f;
      }
    }

    // augment along the alternating path (serial, lane 0)
    WAVE_FENCE();   // way[] relax writes before lane-0 walk
    if (lane == 0) {
      int ja = j0;
      while (ja != 0) { const int jb = way[ja]; p[ja] = p[jb]; ja = jb; }
    }
    WAVE_FENCE();   // p updates (lane 0) before all-lane jp rebuild
    // rebuild the packed jp registers from p (wave-synchronous LDS RAW)
#pragma unroll
    for (int s = 0; s < NSLOT; ++s) {
      const int c = s * 64 + lane;
      if (c < MQ) jp[s] = ((c + 1) << 7) | p[c + 1];
    }
  }

  // extract assignment: cols[row] = column
  WAVE_FENCE();
  for (int j = lane + 1; j <= MQ; j += 64)
    if (p[j] > 0) cols[p[j] - 1] = j - 1;
  WAVE_FENCE();   // cols writes (all lanes) before all-lane ranking reads

  // order = argsort(cols); idx_i = cols[order], idx_j = order
  for (int r = lane; r < NT; r += 64) {
    const int c = cols[r];
    int rank = 0;
    for (int r2 = 0; r2 < NT; ++r2) rank += (cols[r2] < c);
    out_i[b * NT + rank] = (float)c;
    out_j[b * NT + rank] = (float)r;
  }
}

extern "C" void kernel_launch(void* const* d_in, const int* in_sizes, int n_in,
                              void* d_out, int out_size, void* d_ws,
                              size_t ws_size, hipStream_t stream) {
  const float* logits = (const float*)d_in[0];
  const float* boxes  = (const float*)d_in[1];
  const int*   ids    = (const int*)d_in[2];
  const float* tbox   = (const float*)d_in[3];

  float* C     = (float*)d_out;                      // 16*900*1600
  float* out_i = C + (size_t)BS * NQ * NCOL;         // 1600
  float* out_j = out_i + NCOL;                       // 1600

  float* costT = (float*)d_ws;                       // 16*100*900 floats
  float* stats = costT + (size_t)BS * NT * MQ;       // 2 * 14400 floats

  const int id_stride = (in_sizes[2] == 2 * NCOL) ? 2 : 1;

  statcost_kernel<<<BS * NQ, 256, 0, stream>>>(logits, boxes, ids, tbox,
                                               stats, costT, id_stride);
  main_kernel<<<BS * NQ + BS, 256, 0, stream>>>(logits, boxes, ids, tbox,
                                                stats, costT, C, out_i, out_j,
                                                id_stride);
}

// Round 13
// 81.423 us; speedup vs baseline: 3.1469x; 1.7805x over previous
//
#include <hip/hip_runtime.h>
#include <hip/hip_bf16.h>
#include <math.h>

#define BS   16
#define NQ   900
#define NCLS 1000
#define NT   100          // targets per batch (rows for LSA)
#define MQ   900          // queries (cols for LSA)
#define NCOL (BS * NT)    // 1600 total target columns
#define NSLOT 15          // ceil(MQ / 64)

// Compiler-only fence: pins program order of LDS ops around cross-lane
// handoffs. HW DS pipe is in-order per wave, so program order == visibility.
#define WAVE_FENCE() asm volatile("" ::: "memory")

__device__ __forceinline__ unsigned umin32(unsigned a, unsigned b) {
  return a < b ? a : b;
}

template <int CTRL>
__device__ __forceinline__ unsigned dpp_min_u32(unsigned x) {
  const unsigned o = (unsigned)__builtin_amdgcn_update_dpp(
      (int)x, (int)x, CTRL, 0xF, 0xF, false);
  return o < x ? o : x;
}

// full-wave u32 min -> uniform value
__device__ __forceinline__ unsigned wave_min_u32(unsigned x) {
  x = dpp_min_u32<0xB1>(x);    // quad_perm xor1
  x = dpp_min_u32<0x4E>(x);    // quad_perm xor2
  x = dpp_min_u32<0x114>(x);   // row_shr:4
  x = dpp_min_u32<0x118>(x);   // row_shr:8
  x = dpp_min_u32<0x142>(x);   // row_bcast15
  x = dpp_min_u32<0x143>(x);   // row_bcast31
  return (unsigned)__builtin_amdgcn_readlane((int)x, 63);
}

// order-preserving f32 -> u32 (min-compatible)
__device__ __forceinline__ unsigned f32key(float f) {
  unsigned e = __float_as_uint(f);
  return (e & 0x80000000u) ? ~e : (e | 0x80000000u);
}
__device__ __forceinline__ float f32unkey(unsigned k) {
  return __uint_as_float((k & 0x80000000u) ? (k ^ 0x80000000u) : ~k);
}

// ---------------------------------------------------------------------------
// Kernel A: wave-per-row softmax stats + costT diagonal block. No barriers.
// ---------------------------------------------------------------------------
__global__ __launch_bounds__(256) void statcost_kernel(
    const float* __restrict__ logits, const float* __restrict__ boxes,
    const int* __restrict__ ids, const float* __restrict__ tbox,
    float* __restrict__ stats, float* __restrict__ costT, int id_stride) {
  const int tid = threadIdx.x, w = tid >> 6, lane = tid & 63;
  const int row = blockIdx.x * 4 + w;      // 0..14399
  const int b = row / NQ;
  const int q = row - b * NQ;

  __shared__ float lbuf[4][NCLS];
  float* lr = lbuf[w];

  const float4* l4 = (const float4*)(logits + (size_t)row * NCLS);
  float4 vv[4];
  float lmax = -INFINITY;
#pragma unroll
  for (int it = 0; it < 4; ++it) {
    const int idx = it * 64 + lane;
    if (idx < NCLS / 4) {
      vv[it] = l4[idx];
      ((float4*)lr)[idx] = vv[it];
      lmax = fmaxf(lmax,
                   fmaxf(fmaxf(vv[it].x, vv[it].y), fmaxf(vv[it].z, vv[it].w)));
    }
  }
  for (int o = 32; o > 0; o >>= 1) lmax = fmaxf(lmax, __shfl_xor(lmax, o, 64));
  float psum = 0.f;
#pragma unroll
  for (int it = 0; it < 4; ++it) {
    const int idx = it * 64 + lane;
    if (idx < NCLS / 4) {
      psum += expf(vv[it].x - lmax) + expf(vv[it].y - lmax) +
              expf(vv[it].z - lmax) + expf(vv[it].w - lmax);
    }
  }
  for (int o = 32; o > 0; o >>= 1) psum += __shfl_xor(psum, o, 64);
  if (lane == 0) { stats[2 * row] = lmax; stats[2 * row + 1] = psum; }

  WAVE_FENCE();   // LDS stage visible (in-order DS) before gathers
  const float4 bb = *reinterpret_cast<const float4*>(boxes + (size_t)row * 4);
  const float inv = 1.f / psum;
  for (int rr = lane; rr < NT; rr += 64) {
    const int j = b * NT + rr;
    const int id = ids[(size_t)j * id_stride];
    const float4 tb = *reinterpret_cast<const float4*>(tbox + (size_t)j * 4);
    float d = fabsf(bb.x - tb.x);
    d += fabsf(bb.y - tb.y);
    d += fabsf(bb.z - tb.z);
    d += fabsf(bb.w - tb.w);
    costT[((size_t)b * NT + rr) * MQ + q] = d - expf(lr[id] - lmax) * inv;
  }
}

// ---------------------------------------------------------------------------
// Kernel B: per-row minima + argmin of costT. 1600 blocks x 64 lanes.
// ---------------------------------------------------------------------------
__global__ __launch_bounds__(64) void rowmin_kernel(
    const float* __restrict__ costT, float* __restrict__ u_w,
    int* __restrict__ amin_w) {
  const int bid = blockIdx.x;              // b*NT + r
  const float* rowp = costT + (size_t)bid * MQ;
  const int lane = threadIdx.x;
  const unsigned UMAX = 0xFFFFFFFFu;

  unsigned tv[NSLOT];
#pragma unroll
  for (int s = 0; s < NSLOT; ++s) {
    const int c = s * 64 + lane;
    tv[s] = (c < MQ) ? f32key(rowp[c]) : UMAX;
  }
  unsigned m[NSLOT];
#pragma unroll
  for (int s = 0; s < NSLOT; ++s) m[s] = tv[s];
#pragma unroll
  for (int st = 1; st < NSLOT; st <<= 1) {
#pragma unroll
    for (int s = 0; s + st < NSLOT; s += 2 * st) m[s] = umin32(m[s], m[s + st]);
  }
  const unsigned s_vb = wave_min_u32(m[0]);
  unsigned cj[NSLOT];
#pragma unroll
  for (int s = 0; s < NSLOT; ++s)
    cj[s] = (tv[s] == s_vb) ? (unsigned)(s * 64 + lane) : UMAX;
#pragma unroll
  for (int st = 1; st < NSLOT; st <<= 1) {
#pragma unroll
    for (int s = 0; s + st < NSLOT; s += 2 * st)
      cj[s] = umin32(cj[s], cj[s + st]);
  }
  const unsigned s_j = wave_min_u32(cj[0]);
  if (lane == 0) { u_w[bid] = f32unkey(s_vb); amin_w[bid] = (int)s_j; }
}

// ---------------------------------------------------------------------------
// Main kernel: blocks 0..15 = JV LSA (claims from precomputed argmins, ~6
// Dijkstras); blocks 16.. = wave-per-row C-matrix write (overlaps LSA).
// ---------------------------------------------------------------------------
__global__ __launch_bounds__(256) void main_kernel(
    const float* __restrict__ logits, const float* __restrict__ boxes,
    const int* __restrict__ ids, const float* __restrict__ tbox,
    const float* __restrict__ stats, const float* __restrict__ costT,
    const float* __restrict__ u_w, const int* __restrict__ amin_w,
    float* __restrict__ C, float* __restrict__ out_i,
    float* __restrict__ out_j, int id_stride) {
  __shared__ float lbuf[4][NCLS];
  __shared__ int p[MQ + 1];
  __shared__ int way[MQ + 65];   // [901..964] absorb pad writes; [0] dummy
  __shared__ int cols[NT];

  if (blockIdx.x >= BS) {
    // ---------------- C-matrix path (wave-per-row, no barriers) ----------
    const int tid = threadIdx.x, w = tid >> 6, lane = tid & 63;
    const int row = (blockIdx.x - BS) * 4 + w;
    float* lr = lbuf[w];
    const float4* l4 = (const float4*)(logits + (size_t)row * NCLS);
#pragma unroll
    for (int it = 0; it < 4; ++it) {
      const int idx = it * 64 + lane;
      if (idx < NCLS / 4) ((float4*)lr)[idx] = l4[idx];
    }
    WAVE_FENCE();
    const float rmax = stats[2 * row];
    const float inv = 1.f / stats[2 * row + 1];
    const float4 bb = *reinterpret_cast<const float4*>(boxes + (size_t)row * 4);
    float* crow = C + (size_t)row * NCOL;
#pragma unroll 5
    for (int it = 0; it < NCOL / 64; ++it) {
      const int c = it * 64 + lane;
      const int id = ids[(size_t)c * id_stride];
      const float4 tb = *reinterpret_cast<const float4*>(tbox + (size_t)c * 4);
      float d = fabsf(bb.x - tb.x);
      d += fabsf(bb.y - tb.y);
      d += fabsf(bb.z - tb.z);
      d += fabsf(bb.w - tb.w);
      crow[c] = d - expf(lr[id] - rmax) * inv;
    }
    return;
  }

  // ---------------- LSA path: one wave per batch ----------------
  if (threadIdx.x >= 64) return;
  const int b = blockIdx.x;
  const float* cost = costT + (size_t)b * NT * MQ;
  const int lane = threadIdx.x;
  const float FINF = __builtin_inff();
  const unsigned UMAX = 0xFFFFFFFFu;
  const unsigned UINFB = 0x7F800000u;    // +inf f32 bits

  float v[NSLOT];
  unsigned V32[NSLOT];
  float cfA[NSLOT], cfB[NSLOT];
  int jp[NSLOT];                 // (j << 7) | p[j] for this lane's columns

#pragma unroll
  for (int s = 0; s < NSLOT; ++s) v[s] = 0.f;
  for (int j = lane; j <= MQ; j += 64) p[j] = 0;
  for (int r2 = lane; r2 < NT; r2 += 64) cols[r2] = -7777;  // diag sentinel
  WAVE_FENCE();

  // u / amin from rowmin_kernel, distributed to registers
  float u0 = u_w[b * NT + lane];
  float u1 = (lane < NT - 64) ? u_w[b * NT + 64 + lane] : 0.f;
  const int a0 = amin_w[b * NT + lane];
  const int a1 = (lane < NT - 64) ? amin_w[b * NT + 64 + lane] : 0;

  // ---- Greedy pre-assignment, first-row-wins; all state in registers.
  // Claimed edges are tight (cost - rowmin - 0 == 0) -> valid JV duals.
  unsigned long long cl0 = 0, cl1 = 0;   // row-claimed masks (uniform)
  {
    unsigned clm = 0;                    // per-lane claimed-column mask
    for (int r2 = 0; r2 < NT; ++r2) {
      const int aj0 = (r2 < 64) ? __builtin_amdgcn_readlane(a0, r2)
                                : __builtin_amdgcn_readlane(a1, r2 - 64);
      const int slot = aj0 >> 6;
      const bool owner = (lane == (aj0 & 63));
      const unsigned long long bl = __ballot(owner && ((clm >> slot) & 1u));
      if (bl == 0) {                     // column free -> claim it
        if (owner) { clm |= 1u << slot; p[aj0 + 1] = r2 + 1; }
        if (r2 < 64) cl0 |= 1ull << r2;
        else         cl1 |= 1ull << (r2 - 64);
      }
    }
  }
  WAVE_FENCE();   // claim p-writes visible before jp rebuild

  // initial packed jp from the claimed p
#pragma unroll
  for (int s = 0; s < NSLOT; ++s) {
    const int c = s * 64 + lane;
    if (c < MQ) jp[s] = ((c + 1) << 7) | p[c + 1];
  }

  // ---- Dijkstra only for unclaimed rows (~6) ----
  for (int i = 1; i <= NT; ++i) {
    const int r = i - 1;
    const bool skip = (r < 64) ? ((cl0 >> r) & 1ull) : ((cl1 >> (r - 64)) & 1ull);
    if (skip) continue;

    {
      const float* crow = cost + (size_t)r * MQ;
#pragma unroll
      for (int s = 0; s < NSLOT; ++s) {
        const int c = s * 64 + lane;
        cfA[s] = (c < MQ) ? crow[c] : FINF;
      }
    }
    float uir;
    {
      const float uu = (r < 64) ? u0 : u1;
      uir = __uint_as_float(
          (unsigned)__builtin_amdgcn_readlane((int)__float_as_uint(uu),
                                              r & 63));
    }

    unsigned usedm = (lane >= MQ - 14 * 64) ? (1u << 14) : 0u;
    int tm0 = 0, tm1 = 0;
    float D = 0.f;
#pragma unroll
    for (int s = 0; s < NSLOT; ++s) V32[s] = UINFB;
    if (lane == 0) p[0] = i;
    WAVE_FENCE();

    int j0 = 0;
    int i0 = i;
    float ui0 = uir;

    auto iterate = [&](float (&CUR)[NSLOT], float (&NXT)[NSLOT]) -> bool {
      if (j0 > 0) {
        const int cz = j0 - 1;
        const bool own = (lane == (cz & 63));
        usedm |= own ? (1u << (cz >> 6)) : 0u;
      }
      {
        const int ri = i0 - 1;
        tm0 |= (lane == ri) ? 1 : 0;
        tm1 |= (lane == (ri - 64)) ? 1 : 0;
      }

      const float a = ui0 - D;
      unsigned tv[NSLOT];
#pragma unroll
      for (int s = 0; s < NSLOT; ++s) {
        const bool us = (usedm >> s) & 1u;
        const float rel = fmaxf(CUR[s] - a - v[s], 0.f);
        const unsigned rb = __float_as_uint(rel);
        const unsigned rbg = us ? UMAX : rb;
        const bool upd = rbg < V32[s];
        way[upd ? (s * 64 + lane + 1) : 0] = j0;
        V32[s] = upd ? rbg : V32[s];
        tv[s] = us ? UMAX : V32[s];
      }
      unsigned m[NSLOT];
#pragma unroll
      for (int s = 0; s < NSLOT; ++s) m[s] = tv[s];
#pragma unroll
      for (int st = 1; st < NSLOT; st <<= 1) {
#pragma unroll
        for (int s = 0; s + st < NSLOT; s += 2 * st)
          m[s] = umin32(m[s], m[s + st]);
      }
      const unsigned s_best = wave_min_u32(m[0]);
      const float Dnew = __uint_as_float(s_best);

      unsigned cj[NSLOT];
#pragma unroll
      for (int s = 0; s < NSLOT; ++s)
        cj[s] = (tv[s] == s_best) ? (unsigned)jp[s] : UMAX;
#pragma unroll
      for (int st = 1; st < NSLOT; st <<= 1) {
#pragma unroll
        for (int s = 0; s + st < NSLOT; s += 2 * st)
          cj[s] = umin32(cj[s], cj[s + st]);
      }
      const unsigned jpw = wave_min_u32(cj[0]);
      const int j1 = (int)(jpw >> 7);
      const int pj1 = (int)(jpw & 127u);

      if (pj1 != 0) {
        const float* crow = cost + (size_t)(pj1 - 1) * MQ;
#pragma unroll
        for (int s = 0; s < NSLOT; ++s) {
          const int c = s * 64 + lane;
          NXT[s] = (c < MQ) ? crow[c] : FINF;
        }
      }
      float unext = 0.f;
      if (pj1 != 0) {
        const int rr2 = pj1 - 1;
        const float uu = (rr2 < 64) ? u0 : u1;
        unext = __uint_as_float(
            (unsigned)__builtin_amdgcn_readlane((int)__float_as_uint(uu),
                                                rr2 & 63));
      }

      const float delta = Dnew - D;
      D = Dnew;
      u0 += tm0 ? delta : 0.f;
      u1 += tm1 ? delta : 0.f;

      j0 = j1; i0 = pj1; ui0 = unext;
      return pj1 != 0;
    };

    while (true) {
      if (!iterate(cfA, cfB)) break;
      if (!iterate(cfB, cfA)) break;
    }

    // deferred v fixup: used column's use-time offset == frozen V32 value
    {
      const float Dend = D;
#pragma unroll
      for (int s = 0; s < NSLOT; ++s) {
        const int c = s * 64 + lane;
        const bool us = (usedm >> s) & 1u;
        const float dv = __uint_as_float(V32[s]) - Dend;
        v[s] += (us && c < MQ) ? dv : 0.f;
      }
    }

    WAVE_FENCE();   // way[] relax writes before lane-0 walk
    if (lane == 0) {
      int ja = j0;
      while (ja != 0) { const int jb = way[ja]; p[ja] = p[jb]; ja = jb; }
    }
    WAVE_FENCE();   // p updates before all-lane jp rebuild
#pragma unroll
    for (int s = 0; s < NSLOT; ++s) {
      const int c = s * 64 + lane;
      if (c < MQ) jp[s] = ((c + 1) << 7) | p[c + 1];
    }
  }

  // extract assignment: cols[row] = column
  WAVE_FENCE();
  for (int j = lane + 1; j <= MQ; j += 64)
    if (p[j] > 0) cols[p[j] - 1] = j - 1;
  WAVE_FENCE();

  // order = argsort(cols); idx_i = cols[order], idx_j = order
  for (int r = lane; r < NT; r += 64) {
    const int c = cols[r];
    int rank = 0;
    for (int r2 = 0; r2 < NT; ++r2) rank += (cols[r2] < c);
    out_i[b * NT + rank] = (float)c;
    out_j[b * NT + rank] = (float)r;
  }
}

extern "C" void kernel_launch(void* const* d_in, const int* in_sizes, int n_in,
                              void* d_out, int out_size, void* d_ws,
                              size_t ws_size, hipStream_t stream) {
  const float* logits = (const float*)d_in[0];
  const float* boxes  = (const float*)d_in[1];
  const int*   ids    = (const int*)d_in[2];
  const float* tbox   = (const float*)d_in[3];

  float* C     = (float*)d_out;                      // 16*900*1600
  float* out_i = C + (size_t)BS * NQ * NCOL;         // 1600
  float* out_j = out_i + NCOL;                       // 1600

  float* costT = (float*)d_ws;                       // 16*100*900 floats
  float* stats = costT + (size_t)BS * NT * MQ;       // 2 * 14400 floats
  float* u_w   = stats + 2 * BS * NQ;                // 1600 floats
  int*   amin_w = (int*)(u_w + BS * NT);             // 1600 ints

  const int id_stride = (in_sizes[2] == 2 * NCOL) ? 2 : 1;

  statcost_kernel<<<BS * NQ / 4, 256, 0, stream>>>(logits, boxes, ids, tbox,
                                                   stats, costT, id_stride);
  rowmin_kernel<<<BS * NT, 64, 0, stream>>>(costT, u_w, amin_w);
  main_kernel<<<BS * NQ / 4 + BS, 256, 0, stream>>>(
      logits, boxes, ids, tbox, stats, costT, u_w, amin_w, C, out_i, out_j,
      id_stride);
}